// Round 1
// baseline (68.392 us; speedup 1.0000x reference)
//
#include <hip/hip_runtime.h>

#define DIM 256
#define BATCH 131072

#define BM 128
#define BN 256
#define BK 32
#define STRIDE 40   // bf16 elems per LDS row: 32 + 8 pad -> 80 B (16B-aligned, spreads banks)

typedef __attribute__((ext_vector_type(8))) short s16x8;          // 8 bf16 in 4 VGPRs
typedef __attribute__((ext_vector_type(8))) unsigned short u16x8; // 16B load/store
typedef __attribute__((ext_vector_type(4))) float f32x4;

static __device__ __forceinline__ unsigned short f2bf(float f) {
    unsigned int u = __builtin_bit_cast(unsigned int, f);
    u = (u + 0x7FFFu + ((u >> 16) & 1u)) >> 16;   // round-to-nearest-even
    return (unsigned short)u;
}

// ---------------- kernel 1: m = l @ u  (f32, 256x256) ----------------
__global__ void lu_mm(const float* __restrict__ l, const float* __restrict__ u,
                      float* __restrict__ m) {
    __shared__ float sL[DIM];
    const int i = blockIdx.x, j = threadIdx.x;
    sL[j] = l[i * DIM + j];
    __syncthreads();
    float s0 = 0.f, s1 = 0.f, s2 = 0.f, s3 = 0.f;
    #pragma unroll 4
    for (int k = 0; k < DIM; k += 4) {
        s0 = fmaf(sL[k + 0], u[(k + 0) * DIM + j], s0);
        s1 = fmaf(sL[k + 1], u[(k + 1) * DIM + j], s1);
        s2 = fmaf(sL[k + 2], u[(k + 2) * DIM + j], s2);
        s3 = fmaf(sL[k + 3], u[(k + 3) * DIM + j], s3);
    }
    m[i * DIM + j] = (s0 + s1) + (s2 + s3);
}

// -------- kernel 2: w = p @ m (row permutation), store bf16 [n][k] --------
__global__ void perm_conv(const float* __restrict__ p, const float* __restrict__ m,
                          unsigned short* __restrict__ wbt) {
    __shared__ int srcRow;
    const int i = blockIdx.x, j = threadIdx.x;
    if (p[i * DIM + j] != 0.0f) srcRow = j;   // exactly one 1.0 per row
    __syncthreads();
    wbt[i * DIM + j] = f2bf(m[srcRow * DIM + j]);
}

// ---------------- kernel 3: log_det = sum log|diag(u)| ----------------
__global__ void logdet_kernel(const float* __restrict__ u, float* __restrict__ out) {
    const int i = threadIdx.x;
    float v = logf(fabsf(u[i * DIM + i]));
    #pragma unroll
    for (int o = 32; o; o >>= 1) v += __shfl_down(v, o, 64);
    __shared__ float partial[4];
    if ((i & 63) == 0) partial[i >> 6] = v;
    __syncthreads();
    if (i == 0) out[0] = (partial[0] + partial[1]) + (partial[2] + partial[3]);
}

// ---------------- kernel 4: y = x @ w^T  via bf16 MFMA ----------------
// x: [BATCH][256] f32, wbt: [256][256] bf16 (w row-major = B^T layout), y: [BATCH][256] f32
__global__ __launch_bounds__(512) void gemm_xwT(const float* __restrict__ x,
                                                const unsigned short* __restrict__ wbt,
                                                float* __restrict__ y) {
    __shared__ unsigned short sA[BM * STRIDE];
    __shared__ unsigned short sB[BN * STRIDE];

    const int t    = threadIdx.x;
    const int lane = t & 63;
    const int wid  = t >> 6;        // 0..7
    const int wr   = wid >> 2;      // 0..1  (M direction, 64 rows each)
    const int wc   = wid & 3;       // 0..3  (N direction, 64 cols each)
    const int row0 = blockIdx.x * BM;

    // A staging: 4 threads per row (each loads 2x float4 -> 8 bf16)
    const int ar = t >> 2;          // 0..127
    const int ac = (t & 3) * 4;     // 0,4,8,12
    // B staging: 2 threads per row (each loads 2x 16B -> 16 bf16)
    const int br = t >> 1;          // 0..255
    const int bc = (t & 1) * 16;    // 0 or 16

    const int lr = lane & 15;
    const int lg = lane >> 4;

    f32x4 acc[4][4];
    #pragma unroll
    for (int m = 0; m < 4; m++)
        #pragma unroll
        for (int n = 0; n < 4; n++) acc[m][n] = (f32x4){0.f, 0.f, 0.f, 0.f};

    for (int ks = 0; ks < DIM / BK; ++ks) {
        const int k0 = ks * BK;
        if (ks) __syncthreads();
        // ---- stage A: sA[r][k] = bf16(x[row0+r][k0+k]) ----
        {
            const float* src = x + (size_t)(row0 + ar) * DIM + k0 + ac;
            const float4 v0 = *(const float4*)(src);
            const float4 v1 = *(const float4*)(src + 16);
            ushort4 h0 = { f2bf(v0.x), f2bf(v0.y), f2bf(v0.z), f2bf(v0.w) };
            ushort4 h1 = { f2bf(v1.x), f2bf(v1.y), f2bf(v1.z), f2bf(v1.w) };
            *(ushort4*)&sA[ar * STRIDE + ac]      = h0;
            *(ushort4*)&sA[ar * STRIDE + ac + 16] = h1;
        }
        // ---- stage B: sB[n][k] = wbt[n][k0+k] ----
        {
            const unsigned short* src = wbt + br * DIM + k0 + bc;
            const u16x8 w0 = *(const u16x8*)(src);
            const u16x8 w1 = *(const u16x8*)(src + 8);
            *(u16x8*)&sB[br * STRIDE + bc]     = w0;
            *(u16x8*)&sB[br * STRIDE + bc + 8] = w1;
        }
        __syncthreads();

        // ---- fragments + MFMA ----
        s16x8 af[4], bfr[4];
        #pragma unroll
        for (int m = 0; m < 4; m++)
            af[m] = *(const s16x8*)&sA[(wr * 64 + m * 16 + lr) * STRIDE + lg * 8];
        #pragma unroll
        for (int n = 0; n < 4; n++)
            bfr[n] = *(const s16x8*)&sB[(wc * 64 + n * 16 + lr) * STRIDE + lg * 8];
        #pragma unroll
        for (int m = 0; m < 4; m++)
            #pragma unroll
            for (int n = 0; n < 4; n++)
                acc[m][n] = __builtin_amdgcn_mfma_f32_16x16x32_bf16(af[m], bfr[n], acc[m][n], 0, 0, 0);
    }

    // ---- epilogue: C/D layout col=lane&15, row=(lane>>4)*4+j (m89-verified) ----
    #pragma unroll
    for (int m = 0; m < 4; m++) {
        const int gr0 = row0 + wr * 64 + m * 16 + lg * 4;
        #pragma unroll
        for (int n = 0; n < 4; n++) {
            const int gc = wc * 64 + n * 16 + lr;
            #pragma unroll
            for (int j = 0; j < 4; j++)
                y[(size_t)(gr0 + j) * DIM + gc] = acc[m][n][j];
        }
    }
}

extern "C" void kernel_launch(void* const* d_in, const int* in_sizes, int n_in,
                              void* d_out, int out_size, void* d_ws, size_t ws_size,
                              hipStream_t stream) {
    const float* x = (const float*)d_in[0];
    const float* p = (const float*)d_in[1];
    const float* l = (const float*)d_in[2];
    const float* u = (const float*)d_in[3];
    float* out = (float*)d_out;

    float* mtmp = (float*)d_ws;                                            // 256 KB
    unsigned short* wbt = (unsigned short*)((char*)d_ws + DIM * DIM * 4);  // 128 KB

    lu_mm<<<DIM, DIM, 0, stream>>>(l, u, mtmp);
    perm_conv<<<DIM, DIM, 0, stream>>>(p, mtmp, wbt);
    logdet_kernel<<<1, DIM, 0, stream>>>(u, out + (size_t)BATCH * DIM);
    gemm_xwT<<<BATCH / BM, 512, 0, stream>>>(x, wbt, out);
}